// Round 3
// baseline (434.696 us; speedup 1.0000x reference)
//
#include <hip/hip_runtime.h>

#define NN 50000
#define NE 800000
#define CC 128
#define NL 3

typedef short bf16x8 __attribute__((ext_vector_type(8)));
typedef float f32x4 __attribute__((ext_vector_type(4)));
union U16 { uint4 u; bf16x8 v; };

__device__ __forceinline__ float b2f(unsigned short u) {
  return __uint_as_float(((unsigned int)u) << 16);
}
__device__ __forceinline__ unsigned short f2b(float f) {
  unsigned int x = __float_as_uint(f);
  x += 0x7fffu + ((x >> 16) & 1u);   // round-to-nearest-even
  return (unsigned short)(x >> 16);
}

// flags[0] = 1 if float tensors are bf16, 0 if f32.
// flags[1] = 1 if edge_index is int64 (odd 32-bit words all zero), 0 if int32.
__global__ void k_flags(const unsigned short* __restrict__ x,
                        const int* __restrict__ ei, int* __restrict__ flags) {
  __shared__ int cnt, any;
  if (threadIdx.x == 0) { cnt = 0; any = 0; }
  __syncthreads();
  if (threadIdx.x < 128) {
    unsigned short u = x[2 * threadIdx.x];
    int ex = (u >> 7) & 0xFF;
    if (ex >= 0x70 && ex <= 0x8F) atomicAdd(&cnt, 1);
  }
  if (ei[2 * threadIdx.x + 1] != 0) atomicOr(&any, 1);
  __syncthreads();
  if (threadIdx.x == 0) {
    flags[0] = (cnt >= 64) ? 1 : 0;
    flags[1] = (any == 0) ? 1 : 0;
  }
}

__device__ __forceinline__ int eidx(const int* ei, int row, int e, int f64) {
  return f64 ? ei[2 * ((size_t)row * NE + e)] : ei[(size_t)row * NE + e];
}

// ---- x -> bf16 workspace; no-op in bf16 mode (layer 0 reads d_in[0] direct) ----
__global__ __launch_bounds__(256) void k_cvt_x(const void* __restrict__ xin,
                                               unsigned short* __restrict__ xb,
                                               const int* __restrict__ flags) {
  if (flags[0]) return;
  int i = blockIdx.x * 256 + threadIdx.x;   // NN*CC/8 threads exactly
  const float4 a = ((const float4*)xin)[2 * i];
  const float4 b = ((const float4*)xin)[2 * i + 1];
  uint4 o;
  o.x = (unsigned)f2b(a.x) | ((unsigned)f2b(a.y) << 16);
  o.y = (unsigned)f2b(a.z) | ((unsigned)f2b(a.w) << 16);
  o.z = (unsigned)f2b(b.x) | ((unsigned)f2b(b.y) << 16);
  o.w = (unsigned)f2b(b.z) | ((unsigned)f2b(b.w) << 16);
  ((uint4*)xb)[i] = o;
}

// ---- params: W transpose->bf16 (wt[l][n][k]), bias/emlp -> f32 ----
__global__ __launch_bounds__(256) void k_cvt_par(const void* lw, const void* lb,
                                                 const void* emw, const void* emb,
                                                 unsigned short* __restrict__ wt,
                                                 float* lbf, float* emwf, float* embf,
                                                 const int* __restrict__ flags) {
  int i = blockIdx.x * 256 + threadIdx.x;
  const int bf = flags[0];
  if (i < NL * CC * CC) {
    unsigned short v = bf ? ((const unsigned short*)lw)[i]
                          : f2b(((const float*)lw)[i]);
    const int l = i >> 14, r = i & 16383, k = r >> 7, n = r & 127;
    wt[l * 16384 + n * 128 + k] = v;
  }
  if (i < NL * CC)
    lbf[i] = bf ? b2f(((const unsigned short*)lb)[i]) : ((const float*)lb)[i];
  if (i < NL * 8)
    emwf[i] = bf ? b2f(((const unsigned short*)emw)[i]) : ((const float*)emw)[i];
  if (i < NL)
    embf[i] = bf ? b2f(((const unsigned short*)emb)[i]) : ((const float*)emb)[i];
}

// ---- CSR build: histogram of dst + per-edge rank within bucket.
#define HT 8
#define HIST_BLKS ((NE + HT * 256 - 1) / (HT * 256))
__global__ __launch_bounds__(256) void k_hist(const int* __restrict__ ei,
                                              int* __restrict__ deg,
                                              unsigned short* __restrict__ rank,
                                              const int* __restrict__ flags) {
  const int f64 = flags[1];
  const int nt = gridDim.x * 256;
  const int t = blockIdx.x * 256 + threadIdx.x;
  int d[HT], r[HT];
#pragma unroll
  for (int k = 0; k < HT; ++k) {
    const int e = t + k * nt;
    d[k] = (e < NE) ? eidx(ei, 1, e, f64) : -1;
  }
#pragma unroll
  for (int k = 0; k < HT; ++k)
    if (d[k] >= 0) r[k] = atomicAdd(&deg[d[k]], 1);
#pragma unroll
  for (int k = 0; k < HT; ++k) {
    const int e = t + k * nt;
    if (e < NE) rank[e] = (unsigned short)r[k];
  }
}

// ---- 3-phase device-wide exclusive scan over deg[NN] ----
#define NI4 (NN / 4)
#define SCAN_BLKS ((NI4 + 255) / 256)   // 49
__global__ __launch_bounds__(256) void k_scan1(const int* __restrict__ deg,
                                               int* __restrict__ offs,
                                               int* __restrict__ bsum) {
  __shared__ int ls[256];
  const int t = threadIdx.x;
  const int g = blockIdx.x * 256 + t;
  int4 d = make_int4(0, 0, 0, 0);
  if (g < NI4) d = ((const int4*)deg)[g];
  const int s = d.x + d.y + d.z + d.w;
  ls[t] = s;
  __syncthreads();
#pragma unroll
  for (int off = 1; off < 256; off <<= 1) {
    int tmp = (t >= off) ? ls[t - off] : 0;
    __syncthreads();
    ls[t] += tmp;
    __syncthreads();
  }
  const int excl = ls[t] - s;
  if (g < NI4) {
    int4 o;
    o.x = excl; o.y = o.x + d.x; o.z = o.y + d.y; o.w = o.z + d.z;
    ((int4*)offs)[g] = o;
  }
  if (t == 255) bsum[blockIdx.x] = ls[255];
}

__global__ void k_scan2(const int* __restrict__ bsum, int* __restrict__ bbase,
                        int* __restrict__ offs) {
  if (threadIdx.x == 0) {
    int run = 0;
    for (int b = 0; b < SCAN_BLKS; ++b) { bbase[b] = run; run += bsum[b]; }
    offs[NN] = run;
  }
}

__global__ __launch_bounds__(256) void k_scan3(int* __restrict__ offs,
                                               const int* __restrict__ bbase) {
  const int g = blockIdx.x * 256 + threadIdx.x;
  if (g >= NI4) return;
  const int base = bbase[blockIdx.x];
  int4 o = ((int4*)offs)[g];
  o.x += base; o.y += base; o.z += base; o.w += base;
  ((int4*)offs)[g] = o;
}

// ---- CSR fill, ATOMIC-FREE: pos = offs[dst] + rank[e].
//      Record packs BOTH endpoints: (src | dst<<16, w0, w1, w2).
__global__ __launch_bounds__(256) void k_fill(const int* __restrict__ ei,
                                              const void* __restrict__ ea,
                                              const float* __restrict__ emwf,
                                              const float* __restrict__ embf,
                                              const int* __restrict__ offs,
                                              const unsigned short* __restrict__ rank,
                                              uint4* __restrict__ esrt,
                                              const int* __restrict__ flags) {
  int e = blockIdx.x * 256 + threadIdx.x;
  if (e >= NE) return;
  float a[8];
  if (flags[0]) {
    const uint4 v = ((const uint4*)ea)[e];
    unsigned int p[4] = {v.x, v.y, v.z, v.w};
#pragma unroll
    for (int q = 0; q < 4; ++q) {
      a[2 * q]     = __uint_as_float(p[q] << 16);
      a[2 * q + 1] = __uint_as_float(p[q] & 0xffff0000u);
    }
  } else {
    const float4 v0 = ((const float4*)ea)[2 * e];
    const float4 v1 = ((const float4*)ea)[2 * e + 1];
    a[0] = v0.x; a[1] = v0.y; a[2] = v0.z; a[3] = v0.w;
    a[4] = v1.x; a[5] = v1.y; a[6] = v1.z; a[7] = v1.w;
  }
  float w[NL];
#pragma unroll
  for (int l = 0; l < NL; ++l) {
    float z = embf[l];
#pragma unroll
    for (int k = 0; k < 8; ++k) z += a[k] * emwf[l * 8 + k];
    w[l] = (z > 20.f) ? z : log1pf(expf(z));
  }
  const int f64 = flags[1];
  const int d = eidx(ei, 1, e, f64);
  const int s = eidx(ei, 0, e, f64);
  const int pos = offs[d] + (int)rank[e];
  esrt[pos] = make_uint4((unsigned)s | ((unsigned)d << 16),
                         __float_as_uint(w[0]), __float_as_uint(w[1]),
                         __float_as_uint(w[2]));
}

// ---- gather v3: EDGE-parallel segmented reduction.
// Each wave owns a flat chunk of EPW edges (CSR-sorted by dst => runs are
// contiguous). Record loads are address-independent -> batch-8 with one-batch
// prefetch (record latency hides under x-load latency). dst/src/w are
// readfirstlane'd to scalars; x-row loads use saddr form. Segment partials
// (ax - sw*x[dst]) flush via f32 atomicAdd (aggf pre-zeroed).
#define EPW 32
#define GB (EPW / 8)
template<int LAYER>
__device__ __forceinline__ unsigned wcomp(const uint4& p) {
  return LAYER == 0 ? p.y : (LAYER == 1 ? p.z : p.w);
}

template<int LAYER>
__global__ __launch_bounds__(256) void k_gather(const uint4* __restrict__ esrt,
                                                const unsigned short* xb_,
                                                const unsigned short* alt, int sel,
                                                float* __restrict__ aggf,
                                                const int* __restrict__ flags) {
  const unsigned short* xb = (sel && flags[0]) ? alt : xb_;
  const int wv = blockIdx.x * 4 + (threadIdx.x >> 6);
  int e = wv * EPW;                      // NE % EPW == 0
  const int c = (threadIdx.x & 63) * 2;
  float ax = 0.f, ay = 0.f, sw = 0.f;
  int dcur = -1;
  unsigned xdv = 0;                      // prefetched x[dcur] channel pair
  uint4 P[8], Q[8];
#pragma unroll
  for (int k = 0; k < 8; ++k) P[k] = esrt[e + k];
#pragma unroll
  for (int b = 0; b < GB; ++b) {
    unsigned sd[8]; float w8[8];
#pragma unroll
    for (int k = 0; k < 8; ++k) {
      sd[k] = (unsigned)__builtin_amdgcn_readfirstlane((int)P[k].x);
      w8[k] = __uint_as_float(
          (unsigned)__builtin_amdgcn_readfirstlane((int)wcomp<LAYER>(P[k])));
    }
    unsigned v[8];
#pragma unroll
    for (int k = 0; k < 8; ++k) {
      const unsigned short* row = xb + (size_t)(sd[k] & 0xffffu) * CC;
      v[k] = *(const unsigned*)&row[c];
    }
    if (b + 1 < GB) {
#pragma unroll
      for (int k = 0; k < 8; ++k) Q[k] = esrt[e + 8 + k];
    }
#pragma unroll
    for (int k = 0; k < 8; ++k) {
      const int d = (int)(sd[k] >> 16);
      if (d != dcur) {
        if (dcur >= 0) {
          float* ar = aggf + (size_t)dcur * CC + c;
          atomicAdd(ar,     ax - sw * __uint_as_float(xdv << 16));
          atomicAdd(ar + 1, ay - sw * __uint_as_float(xdv & 0xffff0000u));
        }
        ax = 0.f; ay = 0.f; sw = 0.f;
        dcur = d;
        xdv = *(const unsigned*)&xb[(size_t)d * CC + c];  // prefetch x[dst]
      }
      ax += w8[k] * __uint_as_float(v[k] << 16);
      ay += w8[k] * __uint_as_float(v[k] & 0xffff0000u);
      sw += w8[k];
    }
    if (b + 1 < GB) {
#pragma unroll
      for (int k = 0; k < 8; ++k) P[k] = Q[k];
    }
    e += 8;
  }
  if (dcur >= 0) {
    float* ar = aggf + (size_t)dcur * CC + c;
    atomicAdd(ar,     ax - sw * __uint_as_float(xdv << 16));
    atomicAdd(ar + 1, ay - sw * __uint_as_float(xdv & 0xffff0000u));
  }
}

// ---- MFMA gemm: y = aggf(f32) @ W + b; relu+residual -> bf16 xout, or final
//      store. Re-zeroes its aggf tile (next layer's atomic target) when !last.
#define LPAD 136
__global__ __launch_bounds__(256) void k_gemm(float* __restrict__ aggf,
                                              const unsigned short* xc_,
                                              const unsigned short* alt,
                                              int sel,
                                              const unsigned short* __restrict__ wt,
                                              const float* __restrict__ lbf,
                                              int layer, void* outp, int last,
                                              const int* __restrict__ flags,
                                              unsigned short* __restrict__ xout) {
  const unsigned short* xc = (sel && flags[0]) ? alt : xc_;
  __shared__ unsigned short shA[64 * LPAD];    // 17408 B
  __shared__ unsigned short shB[128 * LPAD];   // 34816 B
  const int rb = blockIdx.x * 64;
  const unsigned short* wtl = wt + (size_t)layer * CC * CC;

  for (int u = threadIdx.x; u < 1024; u += 256) {        // A: 64 rows x 16x(8ch)
    const int row = u >> 4, q = u & 15;
    uint4 o = make_uint4(0, 0, 0, 0);
    if (rb + row < NN) {
      const float4 a = *(const float4*)&aggf[(size_t)(rb + row) * CC + q * 8];
      const float4 b = *(const float4*)&aggf[(size_t)(rb + row) * CC + q * 8 + 4];
      o.x = (unsigned)f2b(a.x) | ((unsigned)f2b(a.y) << 16);
      o.y = (unsigned)f2b(a.z) | ((unsigned)f2b(a.w) << 16);
      o.z = (unsigned)f2b(b.x) | ((unsigned)f2b(b.y) << 16);
      o.w = (unsigned)f2b(b.z) | ((unsigned)f2b(b.w) << 16);
    }
    *(uint4*)&shA[row * LPAD + q * 8] = o;
  }
  for (int u = threadIdx.x; u < 2048; u += 256) {        // B: 128 rows x 16 uint4
    const int row = u >> 4, q = u & 15;
    *(uint4*)&shB[row * LPAD + q * 8] = *(const uint4*)&wtl[row * 128 + q * 8];
  }
  __syncthreads();

  if (!last) {   // re-zero this block's aggf tile for the next layer's atomics
    for (int u = threadIdx.x; u < 2048; u += 256) {      // 64 rows x 32 float4
      const int row = u >> 5, q = u & 31;
      if (rb + row < NN)
        *(float4*)&aggf[(size_t)(rb + row) * CC + q * 4] =
            make_float4(0.f, 0.f, 0.f, 0.f);
    }
  }

  const int w = threadIdx.x >> 6;
  const int l = threadIdx.x & 63;
  const int lr = l & 15;
  const int lk = (l >> 4) * 8;

  U16 afr[4];
#pragma unroll
  for (int kk = 0; kk < 4; ++kk)
    afr[kk].u = *(const uint4*)&shA[(w * 16 + lr) * LPAD + kk * 32 + lk];

  const float* lbp = lbf + layer * CC;
  f32x4 acc[8];
#pragma unroll
  for (int t = 0; t < 8; ++t) {
    acc[t] = (f32x4){0.f, 0.f, 0.f, 0.f};
#pragma unroll
    for (int kk = 0; kk < 4; ++kk) {
      U16 bfr;
      bfr.u = *(const uint4*)&shB[(t * 16 + lr) * LPAD + kk * 32 + lk];
      acc[t] = __builtin_amdgcn_mfma_f32_16x16x32_bf16(afr[kk].v, bfr.v, acc[t], 0, 0, 0);
    }
  }

#pragma unroll
  for (int t = 0; t < 8; ++t) {
    const float bv = lbp[t * 16 + lr];
#pragma unroll
    for (int r = 0; r < 4; ++r) {
      const int tr = (l >> 4) * 4 + r;   // C/D: row = quad*4 + reg
      shA[(w * 16 + tr) * LPAD + t * 16 + lr] = f2b(acc[t][r] + bv);
    }
  }
  const int isbf = flags[0];
#pragma unroll
  for (int i = 0; i < 8; ++i) {
    const int idx = i * 64 + l;
    const int row = idx >> 5, cg = idx & 31;
    const int gr = rb + w * 16 + row;
    if (gr >= NN) continue;
    const uint2 yv = *(const uint2*)&shA[(w * 16 + row) * LPAD + cg * 4];
    float y0 = __uint_as_float(yv.x << 16);
    float y1 = __uint_as_float(yv.x & 0xffff0000u);
    float y2 = __uint_as_float(yv.y << 16);
    float y3 = __uint_as_float(yv.y & 0xffff0000u);
    const size_t off = (size_t)gr * CC + cg * 4;
    if (!last) {
      const uint2 rv = *(const uint2*)&xc[off];
      y0 = fmaxf(y0, 0.f) + __uint_as_float(rv.x << 16);
      y1 = fmaxf(y1, 0.f) + __uint_as_float(rv.x & 0xffff0000u);
      y2 = fmaxf(y2, 0.f) + __uint_as_float(rv.y << 16);
      y3 = fmaxf(y3, 0.f) + __uint_as_float(rv.y & 0xffff0000u);
      *(uint2*)&xout[off] = make_uint2((unsigned)f2b(y0) | ((unsigned)f2b(y1) << 16),
                                       (unsigned)f2b(y2) | ((unsigned)f2b(y3) << 16));
    } else if (isbf) {
      *(uint2*)&((unsigned short*)outp)[off] = yv;
    } else {
      *(float4*)&((float*)outp)[off] = make_float4(y0, y1, y2, y3);
    }
  }
}

extern "C" void kernel_launch(void* const* d_in, const int* in_sizes, int n_in,
                              void* d_out, int out_size, void* d_ws, size_t ws_size,
                              hipStream_t stream) {
  const unsigned short* x0 = (const unsigned short*)d_in[0];
  const int* ei = (const int*)d_in[1];

  const size_t nbuf = (size_t)NN * CC;
  unsigned short* xb0 = (unsigned short*)d_ws;
  unsigned short* xb1 = xb0 + nbuf;
  unsigned short* wt = xb1 + nbuf;
  uint4* esrt = (uint4*)(wt + (size_t)NL * CC * CC);
  float* aggf = (float*)(esrt + NE);
  int* deg = (int*)(aggf + nbuf);
  int* offs = deg + NN;
  unsigned short* rank = (unsigned short*)(offs + NN + 4);
  int* bsum = (int*)(rank + NE);
  int* bbase = bsum + 64;
  float* lbf = (float*)(bbase + 64);
  float* emwf = lbf + (size_t)NL * CC;
  float* embf = emwf + NL * 8;
  int* flags = (int*)(embf + NL);
  const size_t need = (size_t)((char*)(flags + 2) - (char*)d_ws);
  if (ws_size < need) {
    hipMemsetAsync(d_out, 0, (size_t)out_size * 2, stream);
    return;
  }

  k_flags<<<1, 256, 0, stream>>>(x0, ei, flags);
  k_cvt_x<<<(NN * CC / 8) / 256, 256, 0, stream>>>(d_in[0], xb0, flags);
  k_cvt_par<<<(NL * CC * CC + 255) / 256, 256, 0, stream>>>(
      d_in[3], d_in[4], d_in[5], d_in[6], wt, lbf, emwf, embf, flags);

  hipMemsetAsync(deg, 0, NN * sizeof(int), stream);
  hipMemsetAsync(aggf, 0, nbuf * sizeof(float), stream);
  k_hist<<<HIST_BLKS, 256, 0, stream>>>(ei, deg, rank, flags);
  k_scan1<<<SCAN_BLKS, 256, 0, stream>>>(deg, offs, bsum);
  k_scan2<<<1, 64, 0, stream>>>(bsum, bbase, offs);
  k_scan3<<<SCAN_BLKS, 256, 0, stream>>>(offs, bbase);
  k_fill<<<(NE + 255) / 256, 256, 0, stream>>>(ei, d_in[2], emwf, embf,
                                               offs, rank, esrt, flags);

  const int GATHER_BLKS = (NE / EPW) / 4;   // 6250
  unsigned short* xc = xb0;
  unsigned short* ag = xb1;
  for (int layer = 0; layer < NL; ++layer) {
    const int sel = (layer == 0) ? 1 : 0;
    if (layer == 0)
      k_gather<0><<<GATHER_BLKS, 256, 0, stream>>>(esrt, xc, x0, sel, aggf, flags);
    else if (layer == 1)
      k_gather<1><<<GATHER_BLKS, 256, 0, stream>>>(esrt, xc, x0, sel, aggf, flags);
    else
      k_gather<2><<<GATHER_BLKS, 256, 0, stream>>>(esrt, xc, x0, sel, aggf, flags);
    k_gemm<<<(NN + 63) / 64, 256, 0, stream>>>(aggf, xc, x0, sel, wt, lbf, layer,
                                               d_out, layer == NL - 1 ? 1 : 0,
                                               flags, ag);
    unsigned short* t = xc; xc = ag; ag = t;   // gemm wrote new x into ag
  }
}

// Round 4
// 308.463 us; speedup vs baseline: 1.4092x; 1.4092x over previous
//
#include <hip/hip_runtime.h>

#define NN 50000
#define NE 800000
#define CC 128
#define NL 3

typedef short bf16x8 __attribute__((ext_vector_type(8)));
typedef float f32x4 __attribute__((ext_vector_type(4)));
union U16 { uint4 u; bf16x8 v; };

__device__ __forceinline__ float b2f(unsigned short u) {
  return __uint_as_float(((unsigned int)u) << 16);
}
__device__ __forceinline__ unsigned short f2b(float f) {
  unsigned int x = __float_as_uint(f);
  x += 0x7fffu + ((x >> 16) & 1u);   // round-to-nearest-even
  return (unsigned short)(x >> 16);
}

// flags[0] = 1 if float tensors are bf16, 0 if f32.
// flags[1] = 1 if edge_index is int64 (odd 32-bit words all zero), 0 if int32.
__global__ void k_flags(const unsigned short* __restrict__ x,
                        const int* __restrict__ ei, int* __restrict__ flags) {
  __shared__ int cnt, any;
  if (threadIdx.x == 0) { cnt = 0; any = 0; }
  __syncthreads();
  if (threadIdx.x < 128) {
    unsigned short u = x[2 * threadIdx.x];
    int ex = (u >> 7) & 0xFF;
    if (ex >= 0x70 && ex <= 0x8F) atomicAdd(&cnt, 1);
  }
  if (ei[2 * threadIdx.x + 1] != 0) atomicOr(&any, 1);
  __syncthreads();
  if (threadIdx.x == 0) {
    flags[0] = (cnt >= 64) ? 1 : 0;
    flags[1] = (any == 0) ? 1 : 0;
  }
}

__device__ __forceinline__ int eidx(const int* ei, int row, int e, int f64) {
  return f64 ? ei[2 * ((size_t)row * NE + e)] : ei[(size_t)row * NE + e];
}

// ---- x -> bf16 workspace; no-op in bf16 mode (layer 0 reads d_in[0] direct) ----
__global__ __launch_bounds__(256) void k_cvt_x(const void* __restrict__ xin,
                                               unsigned short* __restrict__ xb,
                                               const int* __restrict__ flags) {
  if (flags[0]) return;
  int i = blockIdx.x * 256 + threadIdx.x;   // NN*CC/8 threads exactly
  const float4 a = ((const float4*)xin)[2 * i];
  const float4 b = ((const float4*)xin)[2 * i + 1];
  uint4 o;
  o.x = (unsigned)f2b(a.x) | ((unsigned)f2b(a.y) << 16);
  o.y = (unsigned)f2b(a.z) | ((unsigned)f2b(a.w) << 16);
  o.z = (unsigned)f2b(b.x) | ((unsigned)f2b(b.y) << 16);
  o.w = (unsigned)f2b(b.z) | ((unsigned)f2b(b.w) << 16);
  ((uint4*)xb)[i] = o;
}

// ---- params: W transpose->bf16 (wt[l][n][k]), bias/emlp -> f32 ----
__global__ __launch_bounds__(256) void k_cvt_par(const void* lw, const void* lb,
                                                 const void* emw, const void* emb,
                                                 unsigned short* __restrict__ wt,
                                                 float* lbf, float* emwf, float* embf,
                                                 const int* __restrict__ flags) {
  int i = blockIdx.x * 256 + threadIdx.x;
  const int bf = flags[0];
  if (i < NL * CC * CC) {
    unsigned short v = bf ? ((const unsigned short*)lw)[i]
                          : f2b(((const float*)lw)[i]);
    const int l = i >> 14, r = i & 16383, k = r >> 7, n = r & 127;
    wt[l * 16384 + n * 128 + k] = v;
  }
  if (i < NL * CC)
    lbf[i] = bf ? b2f(((const unsigned short*)lb)[i]) : ((const float*)lb)[i];
  if (i < NL * 8)
    emwf[i] = bf ? b2f(((const unsigned short*)emw)[i]) : ((const float*)emw)[i];
  if (i < NL)
    embf[i] = bf ? b2f(((const unsigned short*)emb)[i]) : ((const float*)emb)[i];
}

// ---- CSR build: histogram of dst + per-edge rank within bucket.
#define HT 8
#define HIST_BLKS ((NE + HT * 256 - 1) / (HT * 256))
__global__ __launch_bounds__(256) void k_hist(const int* __restrict__ ei,
                                              int* __restrict__ deg,
                                              unsigned short* __restrict__ rank,
                                              const int* __restrict__ flags) {
  const int f64 = flags[1];
  const int nt = gridDim.x * 256;
  const int t = blockIdx.x * 256 + threadIdx.x;
  int d[HT], r[HT];
#pragma unroll
  for (int k = 0; k < HT; ++k) {
    const int e = t + k * nt;
    d[k] = (e < NE) ? eidx(ei, 1, e, f64) : -1;
  }
#pragma unroll
  for (int k = 0; k < HT; ++k)
    if (d[k] >= 0) r[k] = atomicAdd(&deg[d[k]], 1);
#pragma unroll
  for (int k = 0; k < HT; ++k) {
    const int e = t + k * nt;
    if (e < NE) rank[e] = (unsigned short)r[k];
  }
}

// ---- 3-phase device-wide exclusive scan over deg[NN] ----
#define NI4 (NN / 4)
#define SCAN_BLKS ((NI4 + 255) / 256)   // 49
__global__ __launch_bounds__(256) void k_scan1(const int* __restrict__ deg,
                                               int* __restrict__ offs,
                                               int* __restrict__ bsum) {
  __shared__ int ls[256];
  const int t = threadIdx.x;
  const int g = blockIdx.x * 256 + t;
  int4 d = make_int4(0, 0, 0, 0);
  if (g < NI4) d = ((const int4*)deg)[g];
  const int s = d.x + d.y + d.z + d.w;
  ls[t] = s;
  __syncthreads();
#pragma unroll
  for (int off = 1; off < 256; off <<= 1) {
    int tmp = (t >= off) ? ls[t - off] : 0;
    __syncthreads();
    ls[t] += tmp;
    __syncthreads();
  }
  const int excl = ls[t] - s;
  if (g < NI4) {
    int4 o;
    o.x = excl; o.y = o.x + d.x; o.z = o.y + d.y; o.w = o.z + d.z;
    ((int4*)offs)[g] = o;
  }
  if (t == 255) bsum[blockIdx.x] = ls[255];
}

__global__ void k_scan2(const int* __restrict__ bsum, int* __restrict__ bbase,
                        int* __restrict__ offs) {
  if (threadIdx.x == 0) {
    int run = 0;
    for (int b = 0; b < SCAN_BLKS; ++b) { bbase[b] = run; run += bsum[b]; }
    offs[NN] = run;
  }
}

__global__ __launch_bounds__(256) void k_scan3(int* __restrict__ offs,
                                               const int* __restrict__ bbase) {
  const int g = blockIdx.x * 256 + threadIdx.x;
  if (g >= NI4) return;
  const int base = bbase[blockIdx.x];
  int4 o = ((int4*)offs)[g];
  o.x += base; o.y += base; o.z += base; o.w += base;
  ((int4*)offs)[g] = o;
}

// ---- CSR fill, ATOMIC-FREE: pos = offs[dst] + rank[e];
//      esrt[pos] = (src, w0, w1, w2)
__global__ __launch_bounds__(256) void k_fill(const int* __restrict__ ei,
                                              const void* __restrict__ ea,
                                              const float* __restrict__ emwf,
                                              const float* __restrict__ embf,
                                              const int* __restrict__ offs,
                                              const unsigned short* __restrict__ rank,
                                              uint4* __restrict__ esrt,
                                              const int* __restrict__ flags) {
  int e = blockIdx.x * 256 + threadIdx.x;
  if (e >= NE) return;
  float a[8];
  if (flags[0]) {
    const uint4 v = ((const uint4*)ea)[e];
    unsigned int p[4] = {v.x, v.y, v.z, v.w};
#pragma unroll
    for (int q = 0; q < 4; ++q) {
      a[2 * q]     = __uint_as_float(p[q] << 16);
      a[2 * q + 1] = __uint_as_float(p[q] & 0xffff0000u);
    }
  } else {
    const float4 v0 = ((const float4*)ea)[2 * e];
    const float4 v1 = ((const float4*)ea)[2 * e + 1];
    a[0] = v0.x; a[1] = v0.y; a[2] = v0.z; a[3] = v0.w;
    a[4] = v1.x; a[5] = v1.y; a[6] = v1.z; a[7] = v1.w;
  }
  float w[NL];
#pragma unroll
  for (int l = 0; l < NL; ++l) {
    float z = embf[l];
#pragma unroll
    for (int k = 0; k < 8; ++k) z += a[k] * emwf[l * 8 + k];
    w[l] = (z > 20.f) ? z : log1pf(expf(z));
  }
  const int f64 = flags[1];
  const int d = eidx(ei, 1, e, f64);
  const int s = eidx(ei, 0, e, f64);
  const int pos = offs[d] + (int)rank[e];
  esrt[pos] = make_uint4((unsigned)s, __float_as_uint(w[0]),
                         __float_as_uint(w[1]), __float_as_uint(w[2]));
}

// ---- gather v4: node-parallel, 16-lanes-per-edge-row.
// One wave/node. Lane l: group g=l>>4 (edge slot), channels ch=(l&15)*8.
// One dwordx4 record load fetches 64 records (lane k -> record j+k);
// src/w reach consumer lanes via ds_bpermute (LDS pipe, off the TA path).
// One dwordx4 x-row load serves 4 edges per instruction (16 lanes x 16B each).
// VMEM instrs/node: ~8 vs ~35 in the 1-dword-per-lane version (TA-bound fix).
template<int LAYER>
__device__ __forceinline__ unsigned wcomp(const uint4& p) {
  return LAYER == 0 ? p.y : (LAYER == 1 ? p.z : p.w);
}

template<int LAYER>
__global__ __launch_bounds__(256) void k_gather(const int* __restrict__ offs,
                                                const uint4* __restrict__ esrt,
                                                const unsigned short* xb_,
                                                const unsigned short* alt, int sel,
                                                unsigned short* __restrict__ agg,
                                                const int* __restrict__ flags) {
  const unsigned short* xb = (sel && flags[0]) ? alt : xb_;
  const int node =
      __builtin_amdgcn_readfirstlane(blockIdx.x * 4 + (threadIdx.x >> 6));
  const int l = threadIdx.x & 63;
  const int g = l >> 4;            // edge slot within 4-edge batch
  const int ch = (l & 15) * 8;     // 8 bf16 channels per lane
  const int j0 = offs[node];
  const int j1 = offs[node + 1];

  const uint4 xi = *(const uint4*)&xb[(size_t)node * CC + ch];

  float ax[8];
#pragma unroll
  for (int i = 0; i < 8; ++i) ax[i] = 0.f;
  float sw = 0.f;

  for (int jc = j0; jc < j1; jc += 64) {
    const int cnt = j1 - jc;                   // uniform (1..)
    const int kk = (l < cnt) ? l : (cnt - 1);
    const uint4 rec = esrt[jc + kk];           // 64 records in one instr
    const int srcl = (int)rec.x;
    const int wl = (int)wcomp<LAYER>(rec);
    const int nsb = (cnt + 15) >> 4;           // uniform sub-batch count
    for (int b2 = 0; b2 < nsb; ++b2) {
      int srcw[4]; float wv[4];
#pragma unroll
      for (int b = 0; b < 4; ++b) {
        const int k = b2 * 16 + b * 4 + g;
        srcw[b] = __shfl(srcl, k);
        const float w = __uint_as_float((unsigned)__shfl(wl, k));
        wv[b] = (k < cnt) ? w : 0.f;
      }
      uint4 v[4];
#pragma unroll
      for (int b = 0; b < 4; ++b)
        v[b] = *(const uint4*)&xb[(size_t)(unsigned)srcw[b] * CC + ch];
#pragma unroll
      for (int b = 0; b < 4; ++b) {
        const float w = wv[b];
        const unsigned pv0 = v[b].x, pv1 = v[b].y, pv2 = v[b].z, pv3 = v[b].w;
        ax[0] += w * __uint_as_float(pv0 << 16);
        ax[1] += w * __uint_as_float(pv0 & 0xffff0000u);
        ax[2] += w * __uint_as_float(pv1 << 16);
        ax[3] += w * __uint_as_float(pv1 & 0xffff0000u);
        ax[4] += w * __uint_as_float(pv2 << 16);
        ax[5] += w * __uint_as_float(pv2 & 0xffff0000u);
        ax[6] += w * __uint_as_float(pv3 << 16);
        ax[7] += w * __uint_as_float(pv3 & 0xffff0000u);
        sw += w;
      }
    }
  }

  // combine the 4 edge-slot groups: lanes l, l^16, l^32 hold same channels
#pragma unroll
  for (int i = 0; i < 8; ++i) {
    ax[i] += __shfl_xor(ax[i], 16);
    ax[i] += __shfl_xor(ax[i], 32);
  }
  sw += __shfl_xor(sw, 16);
  sw += __shfl_xor(sw, 32);

  if (l < 16) {
    float r[8];
    r[0] = ax[0] - sw * __uint_as_float(xi.x << 16);
    r[1] = ax[1] - sw * __uint_as_float(xi.x & 0xffff0000u);
    r[2] = ax[2] - sw * __uint_as_float(xi.y << 16);
    r[3] = ax[3] - sw * __uint_as_float(xi.y & 0xffff0000u);
    r[4] = ax[4] - sw * __uint_as_float(xi.z << 16);
    r[5] = ax[5] - sw * __uint_as_float(xi.z & 0xffff0000u);
    r[6] = ax[6] - sw * __uint_as_float(xi.w << 16);
    r[7] = ax[7] - sw * __uint_as_float(xi.w & 0xffff0000u);
    uint4 o;
    o.x = (unsigned)f2b(r[0]) | ((unsigned)f2b(r[1]) << 16);
    o.y = (unsigned)f2b(r[2]) | ((unsigned)f2b(r[3]) << 16);
    o.z = (unsigned)f2b(r[4]) | ((unsigned)f2b(r[5]) << 16);
    o.w = (unsigned)f2b(r[6]) | ((unsigned)f2b(r[7]) << 16);
    *(uint4*)&agg[(size_t)node * CC + ch] = o;
  }
}

// ---- MFMA gemm: y = agg @ W + b; relu+residual -> in-place agg, or final store.
#define LPAD 136
__global__ __launch_bounds__(256) void k_gemm(unsigned short* agg,
                                              const unsigned short* xc_,
                                              const unsigned short* alt,
                                              int sel,
                                              const unsigned short* __restrict__ wt,
                                              const float* __restrict__ lbf,
                                              int layer, void* outp, int last,
                                              const int* __restrict__ flags) {
  const unsigned short* xc = (sel && flags[0]) ? alt : xc_;
  __shared__ unsigned short shA[64 * LPAD];    // 17408 B
  __shared__ unsigned short shB[128 * LPAD];   // 34816 B
  const int rb = blockIdx.x * 64;
  const unsigned short* wtl = wt + (size_t)layer * CC * CC;

  for (int u = threadIdx.x; u < 1024; u += 256) {        // A: 64 rows x 16 uint4
    const int row = u >> 4, q = u & 15;
    uint4 v = make_uint4(0, 0, 0, 0);
    if (rb + row < NN) v = *(const uint4*)&agg[(size_t)(rb + row) * CC + q * 8];
    *(uint4*)&shA[row * LPAD + q * 8] = v;
  }
  for (int u = threadIdx.x; u < 2048; u += 256) {        // B: 128 rows x 16 uint4
    const int row = u >> 4, q = u & 15;
    *(uint4*)&shB[row * LPAD + q * 8] = *(const uint4*)&wtl[row * 128 + q * 8];
  }
  __syncthreads();

  const int w = threadIdx.x >> 6;
  const int l = threadIdx.x & 63;
  const int lr = l & 15;
  const int lk = (l >> 4) * 8;

  U16 afr[4];
#pragma unroll
  for (int kk = 0; kk < 4; ++kk)
    afr[kk].u = *(const uint4*)&shA[(w * 16 + lr) * LPAD + kk * 32 + lk];

  const float* lbp = lbf + layer * CC;
  f32x4 acc[8];
#pragma unroll
  for (int t = 0; t < 8; ++t) {
    acc[t] = (f32x4){0.f, 0.f, 0.f, 0.f};
#pragma unroll
    for (int kk = 0; kk < 4; ++kk) {
      U16 bfr;
      bfr.u = *(const uint4*)&shB[(t * 16 + lr) * LPAD + kk * 32 + lk];
      acc[t] = __builtin_amdgcn_mfma_f32_16x16x32_bf16(afr[kk].v, bfr.v, acc[t], 0, 0, 0);
    }
  }

#pragma unroll
  for (int t = 0; t < 8; ++t) {
    const float bv = lbp[t * 16 + lr];
#pragma unroll
    for (int r = 0; r < 4; ++r) {
      const int tr = (l >> 4) * 4 + r;   // C/D: row = quad*4 + reg
      shA[(w * 16 + tr) * LPAD + t * 16 + lr] = f2b(acc[t][r] + bv);
    }
  }
  const int isbf = flags[0];
#pragma unroll
  for (int i = 0; i < 8; ++i) {
    const int idx = i * 64 + l;
    const int row = idx >> 5, cg = idx & 31;
    const int gr = rb + w * 16 + row;
    if (gr >= NN) continue;
    const uint2 yv = *(const uint2*)&shA[(w * 16 + row) * LPAD + cg * 4];
    float y0 = __uint_as_float(yv.x << 16);
    float y1 = __uint_as_float(yv.x & 0xffff0000u);
    float y2 = __uint_as_float(yv.y << 16);
    float y3 = __uint_as_float(yv.y & 0xffff0000u);
    const size_t off = (size_t)gr * CC + cg * 4;
    if (!last) {
      const uint2 rv = *(const uint2*)&xc[off];
      y0 = fmaxf(y0, 0.f) + __uint_as_float(rv.x << 16);
      y1 = fmaxf(y1, 0.f) + __uint_as_float(rv.x & 0xffff0000u);
      y2 = fmaxf(y2, 0.f) + __uint_as_float(rv.y << 16);
      y3 = fmaxf(y3, 0.f) + __uint_as_float(rv.y & 0xffff0000u);
      *(uint2*)&agg[off] = make_uint2((unsigned)f2b(y0) | ((unsigned)f2b(y1) << 16),
                                      (unsigned)f2b(y2) | ((unsigned)f2b(y3) << 16));
    } else if (isbf) {
      *(uint2*)&((unsigned short*)outp)[off] = yv;
    } else {
      *(float4*)&((float*)outp)[off] = make_float4(y0, y1, y2, y3);
    }
  }
}

extern "C" void kernel_launch(void* const* d_in, const int* in_sizes, int n_in,
                              void* d_out, int out_size, void* d_ws, size_t ws_size,
                              hipStream_t stream) {
  const unsigned short* x0 = (const unsigned short*)d_in[0];
  const int* ei = (const int*)d_in[1];

  const size_t nbuf = (size_t)NN * CC;
  unsigned short* xb0 = (unsigned short*)d_ws;
  unsigned short* xb1 = xb0 + nbuf;
  unsigned short* wt = xb1 + nbuf;
  uint4* esrt = (uint4*)(wt + (size_t)NL * CC * CC);
  int* deg = (int*)(esrt + NE);
  int* offs = deg + NN;
  unsigned short* rank = (unsigned short*)(offs + NN + 4);
  int* bsum = (int*)(rank + NE);
  int* bbase = bsum + 64;
  float* lbf = (float*)(bbase + 64);
  float* emwf = lbf + (size_t)NL * CC;
  float* embf = emwf + NL * 8;
  int* flags = (int*)(embf + NL);
  const size_t need = (size_t)((char*)(flags + 2) - (char*)d_ws);
  if (ws_size < need) {
    hipMemsetAsync(d_out, 0, (size_t)out_size * 2, stream);
    return;
  }

  k_flags<<<1, 256, 0, stream>>>(x0, ei, flags);
  k_cvt_x<<<(NN * CC / 8) / 256, 256, 0, stream>>>(d_in[0], xb0, flags);
  k_cvt_par<<<(NL * CC * CC + 255) / 256, 256, 0, stream>>>(
      d_in[3], d_in[4], d_in[5], d_in[6], wt, lbf, emwf, embf, flags);

  hipMemsetAsync(deg, 0, NN * sizeof(int), stream);
  k_hist<<<HIST_BLKS, 256, 0, stream>>>(ei, deg, rank, flags);
  k_scan1<<<SCAN_BLKS, 256, 0, stream>>>(deg, offs, bsum);
  k_scan2<<<1, 64, 0, stream>>>(bsum, bbase, offs);
  k_scan3<<<SCAN_BLKS, 256, 0, stream>>>(offs, bbase);
  k_fill<<<(NE + 255) / 256, 256, 0, stream>>>(ei, d_in[2], emwf, embf,
                                               offs, rank, esrt, flags);

  unsigned short* xc = xb0;
  unsigned short* ag = xb1;
  for (int layer = 0; layer < NL; ++layer) {
    const int sel = (layer == 0) ? 1 : 0;
    if (layer == 0)
      k_gather<0><<<NN / 4, 256, 0, stream>>>(offs, esrt, xc, x0, sel, ag, flags);
    else if (layer == 1)
      k_gather<1><<<NN / 4, 256, 0, stream>>>(offs, esrt, xc, x0, sel, ag, flags);
    else
      k_gather<2><<<NN / 4, 256, 0, stream>>>(offs, esrt, xc, x0, sel, ag, flags);
    k_gemm<<<(NN + 63) / 64, 256, 0, stream>>>(ag, xc, x0, sel, wt, lbf, layer,
                                               d_out, layer == NL - 1 ? 1 : 0, flags);
    unsigned short* t = xc; xc = ag; ag = t;   // gemm wrote new x into ag
  }
}